// Round 1
// baseline (795.222 us; speedup 1.0000x reference)
//
#include <hip/hip_runtime.h>
#include <stdint.h>

#define NPTS 120000

typedef __attribute__((ext_vector_type(8))) short bf16x8;   // 8 bf16 = 4 VGPR
typedef __attribute__((ext_vector_type(4))) float f32x4;    // MFMA C/D

__device__ __forceinline__ uint16_t f2b(float f) {
    union { float f; uint32_t i; } v; v.f = f;
    uint32_t x = v.i;
    return (uint16_t)((x + 0x7fffu + ((x >> 16) & 1u)) >> 16);   // RNE
}
__device__ __forceinline__ float b2f(uint16_t u) {
    union { uint32_t i; float f; } v; v.i = ((uint32_t)u) << 16; return v.f;
}
__device__ __forceinline__ bf16x8 cvt8(f32x4 a, f32x4 b) {
    bf16x8 t;
    t[0] = (short)f2b(a[0]); t[1] = (short)f2b(a[1]);
    t[2] = (short)f2b(a[2]); t[3] = (short)f2b(a[3]);
    t[4] = (short)f2b(b[0]); t[5] = (short)f2b(b[1]);
    t[6] = (short)f2b(b[2]); t[7] = (short)f2b(b[3]);
    return t;
}
#define MFMA(a, b, c) __builtin_amdgcn_mfma_f32_16x16x32_bf16((a), (b), (c), 0, 0, 0)

// ======================================================================
// Weight swizzle (validated): f32 [K][N] -> bf16 B-frag order,
// flat ((nt*(K/32)+kc)*64 + l)*8 + j. Also zeroes T1 sentinel row NPTS.
// ======================================================================
__global__ __launch_bounds__(256) void k_swz(
    const float* __restrict__ W1s, const float* __restrict__ Wks,
    const float* __restrict__ W2s, const float* __restrict__ Wf,
    uint16_t* __restrict__ Z, uint16_t* __restrict__ T1z)
{
    if (blockIdx.x == 0 && threadIdx.x < 64)
        T1z[(size_t)NPTS * 64 + threadIdx.x] = 0;   // sentinel zero-row
    int idx = blockIdx.x * 256 + threadIdx.x;
    if (idx >= 778240) return;
    const float* src; int K, N, r;
    if (idx < 49152)       { src = W1s + (idx / 8192) * 8192;           K = 128; N = 64;  r = idx & 8191; }
    else if (idx < 712704) { int t = idx - 49152;  src = Wks + (t >> 12) * 4096; K = 64;  N = 64;  r = t & 4095; }
    else if (idx < 761856) { int t = idx - 712704; src = W2s + (t / 8192) * 8192; K = 64;  N = 128; r = t & 8191; }
    else                   { src = Wf; K = 128; N = 128; r = idx - 761856; }
    int j  = r & 7;
    int l  = (r >> 3) & 63;
    int t2 = r >> 9;
    int KC = K >> 5;
    int kc = t2 % KC;
    int nt = t2 / KC;
    int k  = kc * 32 + (l >> 4) * 8 + j;
    int n  = nt * 16 + (l & 15);
    Z[idx] = f2b(src[k * N + n]);
}

// ======================================================================
// T[p][c] = relu(H[p][:] @ W1[:,c]),  K=128, N=64.  (unchanged)
// ======================================================================
__global__ __launch_bounds__(256) void k_gemm1(
    const float* __restrict__ H, const uint16_t* __restrict__ Wz,
    uint16_t* __restrict__ T)
{
    const int tid = threadIdx.x;
    const int wv = tid >> 6, ln = tid & 63;
    const int m = ln & 15, part = ln >> 4;
    const long rb = (long)blockIdx.x * 64 + wv * 16;

    bf16x8 a[4];
    const float* hrow = H + (rb + m) * 128 + part * 8;
    #pragma unroll
    for (int kc = 0; kc < 4; ++kc) {
        f32x4 h0 = *reinterpret_cast<const f32x4*>(hrow + kc * 32);
        f32x4 h1 = *reinterpret_cast<const f32x4*>(hrow + kc * 32 + 4);
        a[kc] = cvt8(h0, h1);
    }
    #pragma unroll
    for (int nt = 0; nt < 4; ++nt) {
        f32x4 acc = (f32x4)(0.0f);
        #pragma unroll
        for (int kc = 0; kc < 4; ++kc) {
            bf16x8 b = *reinterpret_cast<const bf16x8*>(Wz + ((nt * 4 + kc) * 64 + ln) * 8);
            acc = MFMA(a[kc], b, acc);
        }
        #pragma unroll
        for (int r = 0; r < 4; ++r) {
            float v = acc[r] > 0.f ? acc[r] : 0.f;
            T[(rb + part * 4 + r) * 64 + nt * 16 + m] = f2b(v);
        }
    }
}

// ======================================================================
// Fused conv27 + gemm2, RESTRUCTURED: one wave per block, 48 rows/wave,
// wave owns ALL 27 taps (no split-K, no reduction buffer, no barriers).
//   - B-panel reuse x3 retained (3 row-tiles per wave), same L2 weight
//     traffic as the split-K version, but 36 KB red LDS + wave0-serial
//     reduce + 4-way-conflict spills are GONE.
//   - depth-1 software pipeline on the gathered A fragments (ping-pong
//     Aa/Ab): tap k+1's 6 gather loads issue before tap k's 24 MFMAs.
//   - sc2 transpose pad 72->80 shorts (160 B rows: 16B-aligned b128
//     reads, conflict-free b16 writes).
// LDS: snbr 5184 + sc2 7680 = 12864 B. Grid 2500 x 64thr (exact,
// 2500/256CU = 9.77 blocks/CU, balanced). In-place safe (block reads
// Hin only at its own rows, same-lane read-then-write).
// ======================================================================
__global__ __launch_bounds__(64) void k_convg2(
    const uint16_t* __restrict__ T,     // [(NPTS+1)][64] bf16, row NPTS = 0
    const uint16_t* __restrict__ Wkz,   // 27 swizzled 64x64 (4096 each)
    const uint16_t* __restrict__ W2z,   // swizzled 64x128
    const float* Hin,                   // may alias Hout
    const int* __restrict__ nbr,
    float* HoutF, uint16_t* __restrict__ HoutB, int out_bf16)
{
    __shared__ int snbr[48 * 27];                       // 5184 B, [lp][kk]
    __shared__ __align__(16) uint16_t sc2[48 * 80];     // 7680 B
    const int ln = threadIdx.x;                          // 0..63
    const int mrow = ln & 15, part = ln >> 4;
    const int pc8 = part * 8;
    const long bb = (long)blockIdx.x * 48;

    // straight sentinel-transformed copy: snbr[lp*27+kk] = nbr[(bb+lp)*27+kk]
    const int* nb = nbr + bb * 27;
    for (int i = ln; i < 1296; i += 64) {
        int n = nb[i];
        snbr[i] = (n < 0) ? NPTS : n;
    }
    __builtin_amdgcn_wave_barrier();    // compiler fence (single wave, free)

    f32x4 acc[3][4];
    #pragma unroll
    for (int mm = 0; mm < 3; ++mm)
        #pragma unroll
        for (int nt = 0; nt < 4; ++nt) acc[mm][nt] = (f32x4)(0.0f);

    bf16x8 Aa[3][2], Ab[3][2];

#define LOADA(Adst, kk)                                                         \
    {                                                                           \
        _Pragma("unroll")                                                       \
        for (int mm = 0; mm < 3; ++mm) {                                        \
            long r0 = (long)snbr[(mm * 16 + mrow) * 27 + (kk)] << 6;            \
            Adst[mm][0] = *reinterpret_cast<const bf16x8*>(T + r0 + pc8);       \
            Adst[mm][1] = *reinterpret_cast<const bf16x8*>(T + r0 + 32 + pc8);  \
        }                                                                       \
    }

#define TAP(Asrc, kk)                                                           \
    {                                                                           \
        const uint16_t* wb = Wkz + (kk) * 4096;                                 \
        bf16x8 B[8];                                                            \
        _Pragma("unroll")                                                       \
        for (int i = 0; i < 8; ++i)                                             \
            B[i] = *reinterpret_cast<const bf16x8*>(wb + (i * 64 + ln) * 8);    \
        _Pragma("unroll")                                                       \
        for (int nt = 0; nt < 4; ++nt) {                                        \
            _Pragma("unroll")                                                   \
            for (int mm = 0; mm < 3; ++mm) {                                    \
                acc[mm][nt] = MFMA(Asrc[mm][0], B[nt * 2 + 0], acc[mm][nt]);    \
                acc[mm][nt] = MFMA(Asrc[mm][1], B[nt * 2 + 1], acc[mm][nt]);    \
            }                                                                   \
        }                                                                       \
    }

    LOADA(Aa, 0);
    #pragma unroll 1
    for (int k = 0; k < 26; k += 2) {   // k = 0,2,...,24
        LOADA(Ab, k + 1);
        TAP(Aa, k);
        LOADA(Aa, k + 2);               // k+2 <= 26, always valid
        TAP(Ab, k + 1);
    }
    TAP(Aa, 26);
#undef LOADA
#undef TAP

    // transpose: acc (C-layout) -> sc2 (relu, bf16), stride 80 shorts
    #pragma unroll
    for (int mm = 0; mm < 3; ++mm)
        #pragma unroll
        for (int nt = 0; nt < 4; ++nt)
            #pragma unroll
            for (int r = 0; r < 4; ++r) {
                float v = acc[mm][nt][r];
                v = v > 0.f ? v : 0.f;
                sc2[(mm * 16 + part * 4 + r) * 80 + nt * 16 + mrow] = f2b(v);
            }
    __builtin_amdgcn_wave_barrier();    // single wave: no s_barrier needed

    bf16x8 a2[3][2];
    #pragma unroll
    for (int mm = 0; mm < 3; ++mm) {
        const uint16_t* crow = sc2 + (mm * 16 + mrow) * 80;
        a2[mm][0] = *reinterpret_cast<const bf16x8*>(crow + pc8);
        a2[mm][1] = *reinterpret_cast<const bf16x8*>(crow + 32 + pc8);
    }

    // gemm2: K=64, N=128 (8 n-tiles), per-tile epilogue keeps VGPR low
    #pragma unroll 2
    for (int nt = 0; nt < 8; ++nt) {
        bf16x8 b0 = *reinterpret_cast<const bf16x8*>(W2z + ((nt * 2 + 0) * 64 + ln) * 8);
        bf16x8 b1 = *reinterpret_cast<const bf16x8*>(W2z + ((nt * 2 + 1) * 64 + ln) * 8);
        f32x4 c[3];
        #pragma unroll
        for (int mm = 0; mm < 3; ++mm) {
            c[mm] = (f32x4)(0.0f);
            c[mm] = MFMA(a2[mm][0], b0, c[mm]);
            c[mm] = MFMA(a2[mm][1], b1, c[mm]);
        }
        const int col = nt * 16 + mrow;
        if (out_bf16) {
            #pragma unroll
            for (int mm = 0; mm < 3; ++mm)
                #pragma unroll
                for (int r = 0; r < 4; ++r) {
                    long p = bb + mm * 16 + part * 4 + r;
                    float v = c[mm][r] + Hin[p * 128 + col];
                    v = v > 0.f ? v : 0.f;
                    HoutB[p * 128 + col] = f2b(v);
                }
        } else {
            #pragma unroll
            for (int mm = 0; mm < 3; ++mm)
                #pragma unroll
                for (int r = 0; r < 4; ++r) {
                    long p = bb + mm * 16 + part * 4 + r;
                    float v = c[mm][r] + Hin[p * 128 + col];
                    HoutF[p * 128 + col] = v > 0.f ? v : 0.f;
                }
        }
    }
}

// ======================================================================
// Out[p][c] = A[p][c] * sigmoid( B[p][:] @ Wf[:,c] ) + X[p][c]
// (unchanged; in-place safe Out==B)
// ======================================================================
__global__ __launch_bounds__(256) void k_final(
    const float* B, const uint16_t* __restrict__ Wfz,
    const uint16_t* __restrict__ A16, const float* __restrict__ X,
    float* Out)
{
    const int tid = threadIdx.x;
    const int wv = tid >> 6, ln = tid & 63;
    const int m = ln & 15, part = ln >> 4;
    const long rb = (long)blockIdx.x * 64 + wv * 16;

    bf16x8 a[4];
    const float* brow = B + (rb + m) * 128 + part * 8;
    #pragma unroll
    for (int kc = 0; kc < 4; ++kc) {
        f32x4 h0 = *reinterpret_cast<const f32x4*>(brow + kc * 32);
        f32x4 h1 = *reinterpret_cast<const f32x4*>(brow + kc * 32 + 4);
        a[kc] = cvt8(h0, h1);
    }
    #pragma unroll
    for (int nt = 0; nt < 8; ++nt) {
        f32x4 acc = (f32x4)(0.0f);
        #pragma unroll
        for (int kc = 0; kc < 4; ++kc) {
            bf16x8 b = *reinterpret_cast<const bf16x8*>(Wfz + ((nt * 4 + kc) * 64 + ln) * 8);
            acc = MFMA(a[kc], b, acc);
        }
        #pragma unroll
        for (int r = 0; r < 4; ++r) {
            long p = rb + part * 4 + r;
            int col = nt * 16 + m;
            float s = 1.f / (1.f + __expf(-acc[r]));
            float av = b2f(A16[p * 128 + col]);
            Out[p * 128 + col] = av * s + X[p * 128 + col];
        }
    }
}

// ======================================================================
// ws: A16 (NPTS*128 bf16) | T1 ((NPTS+1)*64 bf16, sentinel) | Z (778240)
//   ≈ 47.6 MB.
// ======================================================================
extern "C" void kernel_launch(void* const* d_in, const int* in_sizes, int n_in,
                              void* d_out, int out_size, void* d_ws, size_t ws_size,
                              hipStream_t stream)
{
    const float* x   = (const float*)d_in[0];
    const float* W1s = (const float*)d_in[1];
    const float* Wks = (const float*)d_in[2];
    const float* W2s = (const float*)d_in[3];
    const float* Wf  = (const float*)d_in[4];
    const int*   nbr = (const int*)d_in[5];
    float*       out = (float*)d_out;

    uint16_t* A16 = (uint16_t*)d_ws;                       // NPTS*128
    uint16_t* T1  = A16 + (size_t)NPTS * 128;              // (NPTS+1)*64
    uint16_t* Z   = T1 + (size_t)(NPTS + 1) * 64;          // 778240
    const uint16_t* W1z = Z;
    const uint16_t* Wkz = Z + 49152;
    const uint16_t* W2z = Z + 712704;
    const uint16_t* Wfz = Z + 761856;

    k_swz<<<dim3(3040), dim3(256), 0, stream>>>(W1s, Wks, W2s, Wf, Z, T1);

    auto unit = [&](int i, const float* hin, float* houtF, uint16_t* houtB, int obf) {
        k_gemm1<<<dim3(1875), dim3(256), 0, stream>>>(hin, W1z + (size_t)i * 8192, T1);
        k_convg2<<<dim3(2500), dim3(64), 0, stream>>>(T1, Wkz + (size_t)i * 110592,
                                                      W2z + (size_t)i * 8192,
                                                      hin, nbr, houtF, houtB, obf);
    };

    // branch a (h in d_out); unit 2 also emits aRes bf16 -> A16
    unit(0, x,   out, nullptr, 0);
    unit(1, out, out, nullptr, 0);
    unit(2, out, out, A16,     1);
    // branch b (h in d_out, reused)
    unit(3, x,   out, nullptr, 0);
    unit(4, out, out, nullptr, 0);
    unit(5, out, out, nullptr, 0);
    // out = aRes * sigmoid(bRes @ Wf) + x
    k_final<<<dim3(1875), dim3(256), 0, stream>>>(out, Wfz, A16, x, out);
}